// Round 5
// baseline (103.092 us; speedup 1.0000x reference)
//
#include <hip/hip_runtime.h>
#include <math.h>

// Morphological dilation, k=4x4, TF SAME padding (pad top/left=1, bottom/right=2).
// x: (8, 512, 512, 32) fp32 NHWC;  w: (4, 4, 32) fp32;  out: same as x.
// out[b,y,x,c] = max_{i,j} x[b, y+i-1, x+j-1, c] + w[i,j,c]  (OOB -> -inf)
//
// R5: rolling-ring accumulator. Thread owns (c,x) and walks a 128-row y-chunk;
// input row yy feeds output rows yy+1..yy-2 (i=0..3) held in a 4-slot ring.
// After yy, out row yy-2 is complete -> NT store, slot reset for row yy+2.
// Read halo: 131/128 = 1.023x (vs 1.19x at T=16). ~40 VGPR -> 8 waves/SIMD;
// 2048 blocks x 4 waves = exactly 100% residency, uniform duration.

constexpr int H = 512;
constexpr int W = 512;
constexpr int C = 32;
constexpr int CHUNK = 128;   // y rows per thread

// One input row yy (phase P = yy & 3). Slot assignment (all compile-time):
//   y = yy+1 -> slot (P+1)&3   (i=0)
//   y = yy   -> slot  P        (i=1)
//   y = yy-1 -> slot (P+3)&3   (i=2)
//   y = yy-2 -> slot (P+2)&3   (i=3) -- completed: store (if STORE) + reset.
template<int P, bool STORE, bool XEDGE>
__device__ __forceinline__ void step(const float* __restrict__ xb,
                                     float* __restrict__ ob,
                                     const float wv[16], float acc[4],
                                     const int yy, const int xp) {
    constexpr int S0 = P;
    constexpr int S1 = (P + 1) & 3;
    constexpr int S2 = (P + 2) & 3;
    constexpr int S3 = (P + 3) & 3;
    const float NI = -INFINITY;

    const bool yok = ((unsigned)yy < (unsigned)H);     // uniform -> SALU
    const int  yc  = min(max(yy, 0), H - 1);
    const float* rowp = xb + (size_t)yc * (W * C);

    float px[4];
#pragma unroll
    for (int j = 0; j < 4; ++j) {
        int xx = xp + j - 1;
        bool ok = yok;
        if (XEDGE) {
            ok = ok & ((unsigned)xx < (unsigned)W);
            xx = min(max(xx, 0), W - 1);
        }
        float v = rowp[(size_t)xx * C];
        px[j] = ok ? v : NI;
    }

    acc[S1] = fmaxf(acc[S1], fmaxf(fmaxf(px[0] + wv[ 0], px[1] + wv[ 1]),
                                   fmaxf(px[2] + wv[ 2], px[3] + wv[ 3])));
    acc[S0] = fmaxf(acc[S0], fmaxf(fmaxf(px[0] + wv[ 4], px[1] + wv[ 5]),
                                   fmaxf(px[2] + wv[ 6], px[3] + wv[ 7])));
    acc[S3] = fmaxf(acc[S3], fmaxf(fmaxf(px[0] + wv[ 8], px[1] + wv[ 9]),
                                   fmaxf(px[2] + wv[10], px[3] + wv[11])));
    acc[S2] = fmaxf(acc[S2], fmaxf(fmaxf(px[0] + wv[12], px[1] + wv[13]),
                                   fmaxf(px[2] + wv[14], px[3] + wv[15])));

    if (STORE)
        __builtin_nontemporal_store(acc[S2], ob + (size_t)(yy - 2) * (W * C));
    acc[S2] = NI;   // slot reused for output row yy+2
}

template<bool XEDGE>
__device__ __forceinline__ void chunk_body(const float* __restrict__ xb,
                                           float* __restrict__ ob,
                                           const float wv[16], float acc[4],
                                           const int y0, const int xp) {
    // prologue: rows y0-1, y0, y0+1 — accumulate, reset retired slot, no store
    step<3, false, XEDGE>(xb, ob, wv, acc, y0 - 1, xp);
    step<0, false, XEDGE>(xb, ob, wv, acc, y0,     xp);
    step<1, false, XEDGE>(xb, ob, wv, acc, y0 + 1, xp);
    // steady: rows y0+2 .. y0+129 store outputs y0 .. y0+127
    for (int s = 0; s < CHUNK; s += 4) {
        const int yy = y0 + 2 + s;
        step<2, true, XEDGE>(xb, ob, wv, acc, yy,     xp);
        step<3, true, XEDGE>(xb, ob, wv, acc, yy + 1, xp);
        step<0, true, XEDGE>(xb, ob, wv, acc, yy + 2, xp);
        step<1, true, XEDGE>(xb, ob, wv, acc, yy + 3, xp);
    }
}

__global__ __launch_bounds__(256)
void dil2d_kernel(const float* __restrict__ xin,
                  const float* __restrict__ wt,
                  float* __restrict__ out) {
    // thread -> (channel, x): lanes walk c then x -> 256 B contiguous per wave load
    const int c  = threadIdx.x & (C - 1);        // 0..31
    const int xl = threadIdx.x >> 5;             // 0..7
    const int xp = blockIdx.x * 8 + xl;          // 0..511
    const int y0 = blockIdx.y * CHUNK;           // chunk start row (mult of 4)
    const int b  = blockIdx.z;

    // 4x4 weight taps for our channel in registers (16 VGPRs)
    float wv[16];
#pragma unroll
    for (int k = 0; k < 16; ++k)
        wv[k] = wt[k * C + c];

    float acc[4] = { -INFINITY, -INFINITY, -INFINITY, -INFINITY };

    const float* xb = xin + (size_t)b * H * W * C + c;
    float* ob = out + ((size_t)b * H * W + xp) * C + c;

    const bool xedge = (blockIdx.x == 0) || (blockIdx.x == gridDim.x - 1);
    if (xedge) chunk_body<true >(xb, ob, wv, acc, y0, xp);
    else       chunk_body<false>(xb, ob, wv, acc, y0, xp);
}

extern "C" void kernel_launch(void* const* d_in, const int* in_sizes, int n_in,
                              void* d_out, int out_size, void* d_ws, size_t ws_size,
                              hipStream_t stream) {
    const float* x = (const float*)d_in[0];
    const float* w = (const float*)d_in[1];
    float* o = (float*)d_out;

    dim3 block(256);
    dim3 grid(W / 8,        // 64: x tiles (8 x-positions per block)
              H / CHUNK,    // 4:  y chunks
              8);           // batch
    dil2d_kernel<<<grid, block, 0, stream>>>(x, w, o);
}